// Round 10
// baseline (12374.896 us; speedup 1.0000x reference)
//
#include <hip/hip_runtime.h>

#define B_N 16
#define T_N 15
#define CIN 64
#define COUT 128
#define HS 56
#define HWN 3136
#define NSG (16 * 128 * 28 * 28)  // 1,605,632 pooled sites

// Reference model (XLA:CPU / Eigen conv):
//   conv k-order = (kh, kw, ci) with ci innermost, ONE flat sequential FMA
//   chain per output element (single Eigen K-panel at K=576), bias added as
//   a separate rounded op. Elementwise/scan ops: per-op rounding, no FMA.

// ---------- weight transpose: w[co][ci][kh][kw] -> wt[k][co],
//            k = (kh*3+kw)*64 + ci  (kh-major, ci-minor, Eigen patch order)
__global__ void wt_kernel(const float* __restrict__ w, float* __restrict__ wt) {
    int i = blockIdx.x * 256 + threadIdx.x;  // 0 .. 73727
    if (i >= COUT * 576) return;
    int co = i / 576;
    int r = i - co * 576;          // r = ci*9 + kh*3 + kw (source layout)
    int ci = r / 9;
    int kk = r - ci * 9;           // kh*3+kw
    wt[(kk * CIN + ci) * COUT + co] = w[i];
}

// ---------- naive conv, strict fp32, flat FMA chain in (kh,kw,ci) order ----
// One thread per (pixel, co). Block 256 = 2 pixels x 128 co.
__global__ __launch_bounds__(256) void conv_naive32(
    const float* __restrict__ x, const float* __restrict__ wt,
    const float* __restrict__ bias, float* __restrict__ obuf,
    int t, int b0)
{
    const int tid = threadIdx.x;
    const int co = tid & 127;
    const long p = (long)blockIdx.x * 2 + (tid >> 7);
    const int bl = (int)(p / HWN);
    const int hw = (int)(p - (long)bl * HWN);
    const int h = hw / HS;
    const int wq = hw - h * HS;
    const int b = b0 + bl;

    const float* xb = x + ((size_t)(b * T_N + t) * CIN) * HWN;

    float acc = 0.0f;
#pragma unroll
    for (int kh = 0; kh < 3; ++kh) {
        const int gh = h - 1 + kh;
        if ((unsigned)gh >= (unsigned)HS) continue;   // zero rows: FMA no-op
#pragma unroll
        for (int kw = 0; kw < 3; ++kw) {
            const int gw = wq - 1 + kw;
            if ((unsigned)gw >= (unsigned)HS) continue;
            const float* xc = xb + gh * HS + gw;                 // + ci*HWN
            const float* wk = wt + ((kh * 3 + kw) * CIN) * COUT + co;
            for (int ci = 0; ci < CIN; ++ci) {
                // strictly sequential fused multiply-add (Eigen gebp chain)
                acc = fmaf(xc[(size_t)ci * HWN], wk[ci * COUT], acc);
            }
        }
    }
    obuf[((size_t)bl * COUT + co) * HWN + hw] = __fadd_rn(acc, bias[co]);
}

// ---------- recurrence step, strict fp32 (verified elementwise chain) ----
__global__ __launch_bounds__(256) void rec_step32(
    const float* __restrict__ cvbuf, const float* __restrict__ fcw,
    const float* __restrict__ fcb, float* __restrict__ stateD,
    unsigned* __restrict__ stateS, float* __restrict__ out,
    int t, int b0, int doLoad, int doStore)
{
    const int idx = blockIdx.x * 256 + threadIdx.x;  // nb*128*784 sites
    const int pw = idx % 28;
    int tmp = idx / 28;
    const int ph = tmp % 28;
    tmp /= 28;
    const int co = tmp & 127;
    const int bl = tmp >> 7;
    const int b = b0 + bl;

    const size_t g = ((size_t)(b * COUT + co)) * 784 + ph * 28 + pw;

    const float w0 = fcw[0], w1 = fcw[1], w2 = fcw[2], fb = fcb[0];

    float u[4], m3[4], s[4];
    if (doLoad) {
        unsigned sm = stateS[g];
#pragma unroll
        for (int p = 0; p < 4; ++p) {
            u[p] = stateD[(size_t)p * NSG + g];
            m3[p] = stateD[(size_t)(4 + p) * NSG + g];
            s[p] = (float)((sm >> p) & 1u);
        }
    } else {
#pragma unroll
        for (int p = 0; p < 4; ++p) { u[p] = 0.0f; m3[p] = 0.0f; s[p] = 0.0f; }
    }

    const int h0 = ph * 2, wc0 = pw * 2;
    const size_t cbase = ((size_t)(bl * COUT + co)) * HWN + (size_t)h0 * HS + wc0;
    const float cv[4] = {cvbuf[cbase], cvbuf[cbase + 1],
                         cvbuf[cbase + HS], cvbuf[cbase + HS + 1]};

#pragma unroll
    for (int p = 0; p < 4; ++p) {
        // x4 = einsum(old mem[0:3], w) + fb : per-op rounding, no FMA
        float e0 = __fadd_rn(__fadd_rn(__fmul_rn(u[p], w0), __fmul_rn(u[p], w1)),
                             __fmul_rn(u[p], w2));
        float x4 = __fadd_rn(e0, fb);
        // dd = 0.2*(1-spike)
        float dd = __fmul_rn(0.2f, __fsub_rn(1.0f, s[p]));
        // new03 = u*dd + conv ; new3 = m3*dd + x4
        u[p]  = __fadd_rn(__fmul_rn(u[p], dd), cv[p]);
        m3[p] = __fadd_rn(__fmul_rn(m3[p], dd), x4);
        // mem1 = (einsum(new03) + fb) + new3
        float e1 = __fadd_rn(__fadd_rn(__fmul_rn(u[p], w0), __fmul_rn(u[p], w1)),
                             __fmul_rn(u[p], w2));
        float mem1 = __fadd_rn(__fadd_rn(e1, fb), m3[p]);
        // spike = (mem1 - 0.8 > 0)
        s[p] = (__fsub_rn(mem1, 0.8f) > 0.0f) ? 1.0f : 0.0f;
    }

    float pooled = 0.25f * (((s[0] + s[1]) + s[2]) + s[3]);  // exact on 0/1
    out[(((size_t)b * T_N + t) * COUT + co) * 784 + ph * 28 + pw] = pooled;

    if (doStore) {
        unsigned sm = 0;
#pragma unroll
        for (int p = 0; p < 4; ++p) {
            stateD[(size_t)p * NSG + g] = u[p];
            stateD[(size_t)(4 + p) * NSG + g] = m3[p];
            sm |= (s[p] > 0.5f) ? (1u << p) : 0u;
        }
        stateS[g] = sm;
    }
}

extern "C" void kernel_launch(void* const* d_in, const int* in_sizes, int n_in,
                              void* d_out, int out_size, void* d_ws, size_t ws_size,
                              hipStream_t stream) {
    const float* x     = (const float*)d_in[0];
    const float* cw    = (const float*)d_in[1];
    const float* cbias = (const float*)d_in[2];
    const float* fcw   = (const float*)d_in[3];
    const float* fcb   = (const float*)d_in[4];
    float* out = (float*)d_out;

    const size_t wtB    = (size_t)COUT * 576 * sizeof(float);   // 294 KB
    const size_t planeB = (size_t)COUT * HWN * sizeof(float);   // 1.606 MB per b
    const size_t statB  = (size_t)NSG * 8 * sizeof(float)       // u,m3 planes
                        + (size_t)NSG * sizeof(unsigned);       // spike bits (~57.8 MB)

    int nb = 0;
    for (int c = B_N; c >= 1; c >>= 1) {
        if (wtB + (size_t)c * planeB + statB <= ws_size) { nb = c; break; }
    }
    if (!nb) return;  // ws unusably small (< ~60 MB)

    float* wt = (float*)d_ws;
    float* convbuf = (float*)((char*)d_ws + wtB);
    float* stateD = (float*)((char*)d_ws + wtB + (size_t)nb * planeB);
    unsigned* stateS = (unsigned*)((char*)stateD + (size_t)NSG * 8 * sizeof(float));

    wt_kernel<<<(COUT * 576 + 255) / 256, 256, 0, stream>>>(cw, wt);

    for (int t = 0; t < T_N; ++t) {
        for (int b0 = 0; b0 < B_N; b0 += nb) {
            int nbc = (B_N - b0 < nb) ? (B_N - b0) : nb;
            conv_naive32<<<nbc * (HWN / 2), 256, 0, stream>>>(x, wt, cbias, convbuf, t, b0);
            rec_step32<<<nbc * 128 * 784 / 256, 256, 0, stream>>>(
                convbuf, fcw, fcb, stateD, stateS, out,
                t, b0, t > 0 ? 1 : 0, t < T_N - 1 ? 1 : 0);
        }
    }
}